// Round 8
// baseline (1069.528 us; speedup 1.0000x reference)
//
#include <hip/hip_runtime.h>

// Fused GQA attention layer for MI355X (gfx950).
// B=2 S=2048 E=4096 HQ=32 HKV=8 D=128 WINDOW=1024 SOFT_CAP=50 Q_PRE_ATTN=128
//
// R12:
//  * QKV GEMM reverted to gemm256 (227us known; R11's gemm_bk32 = 259us:
//    8-lane-group bank conflicts (2.5e7) + 1.5x fetch + vmcnt(0)).
//  * attn_fwd v4: BARRIER-FREE. Each wave independent: 16 queries, K/V
//    fragments loaded directly from global (L2-resident 0.5MB planes; the
//    global slot per fragment = what the verified R6 LDS swizzle resolved
//    to, so MFMA layouts are unchanged). Wave-private LDS P-transpose only
//    (8KB/block). launch_bounds(256,4) -> 16 indep waves/CU (TLP hiding).
//    Mechanism: R7/R8/R10 all kept block-wide barrier-per-tile serial
//    chains (implied MfmaUtil ~12%); this removes inter-wave coupling.
//
// Workspace layout (160 MiB, regions reused over time):
//   [0,        33.5M)  xb        -> later vtb
//   [33.5M,    83.9M)  WqkvT     -> later qb|kb
//   [83.9M,   117.4M)  WoT       (persistent)
//   [117.4M,  167.8M)  qkv_raw   -> later attn

typedef unsigned short u16;
typedef unsigned int   u32;
typedef __bf16 bf16x8 __attribute__((ext_vector_type(8)));
typedef float  f32x4  __attribute__((ext_vector_type(4)));

typedef __attribute__((address_space(1))) void* gas_ptr;
typedef __attribute__((address_space(3))) void* las_ptr;

__device__ __forceinline__ void load_lds16(const void* g, void* l) {
  __builtin_amdgcn_global_load_lds((gas_ptr)g, (las_ptr)l, 16, 0, 0);
}

__device__ __forceinline__ u16 f2bf(float f) {
  u32 u = __builtin_bit_cast(u32, f);
  u += 0x7fffu + ((u >> 16) & 1u);   // RNE
  return (u16)(u >> 16);
}
__device__ __forceinline__ float bf2f(u16 h) {
  u32 u = ((u32)h) << 16;
  return __builtin_bit_cast(float, u);
}
// truncate-pack two fp32 -> bf16 pair (low = a, high = b)
__device__ __forceinline__ u32 pack_trunc(float a, float b) {
  return (__builtin_bit_cast(u32, a) >> 16) | (__builtin_bit_cast(u32, b) & 0xffff0000u);
}

// ---------------------------------------------------------------- cast x
__global__ __launch_bounds__(256) void cast_f32_bf16(const float* __restrict__ src,
                                                     u16* __restrict__ dst) {
  size_t i = ((size_t)blockIdx.x * 256 + threadIdx.x) * 8;
  float4 a = *(const float4*)(src + i);
  float4 b = *(const float4*)(src + i + 4);
  uint4 o;
  o.x = (u32)f2bf(a.x) | ((u32)f2bf(a.y) << 16);
  o.y = (u32)f2bf(a.z) | ((u32)f2bf(a.w) << 16);
  o.z = (u32)f2bf(b.x) | ((u32)f2bf(b.y) << 16);
  o.w = (u32)f2bf(b.z) | ((u32)f2bf(b.w) << 16);
  *(uint4*)(dst + i) = o;
}

// ------------------------------------------------- transpose-cast fp32->bf16
__global__ __launch_bounds__(256) void transpose_cast_f32_bf16(
    const float* __restrict__ src, u16* __restrict__ dst, int R, int C) {
  __shared__ float tile[32][33];
  const int tx = threadIdx.x & 31, ty = threadIdx.x >> 5;
  const int r0 = blockIdx.y * 32, c0 = blockIdx.x * 32;
#pragma unroll
  for (int i = 0; i < 4; ++i)
    tile[ty + i * 8][tx] = src[(size_t)(r0 + ty + i * 8) * C + (c0 + tx)];
  __syncthreads();
  const int cc = threadIdx.x >> 3;       // output row (src col) 0..31
  const int rg = threadIdx.x & 7;        // 4-elem group along r
  uint2 ov;
  ov.x = (u32)f2bf(tile[rg * 4 + 0][cc]) | ((u32)f2bf(tile[rg * 4 + 1][cc]) << 16);
  ov.y = (u32)f2bf(tile[rg * 4 + 2][cc]) | ((u32)f2bf(tile[rg * 4 + 3][cc]) << 16);
  *(uint2*)&dst[(size_t)(c0 + cc) * R + (r0 + rg * 4)] = ov;
}

// ------------------------------------------------- V plane transpose from qkvr
__global__ __launch_bounds__(256) void transpose_v(const u16* __restrict__ qkvr,
                                                   u16* __restrict__ vtb) {
  __shared__ u16 tile[32][34];
  const int plane = blockIdx.z;
  const int b = plane >> 3, h8 = plane & 7;
  const u16* s = qkvr + (size_t)(b * 2048) * 6144 + (40 + h8) * 128;
  u16* d = vtb + (size_t)plane * 2048 * 128;
  const int tx = threadIdx.x & 31, ty = threadIdx.x >> 5;
  const int r0 = blockIdx.x * 32, c0 = blockIdx.y * 32;   // r=pos, c=d
#pragma unroll
  for (int i = 0; i < 4; ++i)
    tile[ty + i * 8][tx] = s[(size_t)(r0 + ty + i * 8) * 6144 + (c0 + tx)];
  __syncthreads();
  const int cc = threadIdx.x >> 3;
  const int rg = threadIdx.x & 7;
  uint2 ov;
  ov.x = (u32)tile[rg * 4 + 0][cc] | ((u32)tile[rg * 4 + 1][cc] << 16);
  ov.y = (u32)tile[rg * 4 + 2][cc] | ((u32)tile[rg * 4 + 3][cc] << 16);
  *(uint2*)&d[(size_t)(c0 + cc) * 2048 + (r0 + rg * 4)] = ov;
}

// ---------------------------------------------------------------- GEMM 256^2 8-phase
// (both GEMMs; measured-stable: QKV 227us @384 blocks, out ~1 round @256)

template <int MB>
__device__ __forceinline__ void mm16(f32x4 (&acc)[8][4], const bf16x8 (&af)[4],
                                     const bf16x8 (&bf)[4]) {
#pragma unroll
  for (int ii = 0; ii < 4; ++ii)
#pragma unroll
    for (int nf = 0; nf < 4; ++nf)
      acc[MB + ii][nf] =
          __builtin_amdgcn_mfma_f32_16x16x32_bf16(af[ii], bf[nf], acc[MB + ii][nf], 0, 0, 0);
}

template <int OUT_BF16>
__global__ __launch_bounds__(512, 2) void gemm256(const u16* __restrict__ A,
                                                  const u16* __restrict__ Bt,
                                                  void* __restrict__ Cout,
                                                  int N, int K, int ntx) {
  __shared__ __align__(16) u16 lds[65536];   // 128 KiB
  const int t = threadIdx.x, lane = t & 63, w = t >> 6;
  const int c = lane & 15, q = lane >> 4;
  const int wm = w >> 2, wn = w & 3;

  const int cpx = (int)gridDim.x >> 3;
  const int swz = ((int)blockIdx.x & 7) * cpx + ((int)blockIdx.x >> 3);
  const int bx = swz % ntx, by = swz / ntx;
  const int m0 = by << 8, n0 = bx << 8;

  u32 aoff[2][2], boff[2][2];
#pragma unroll
  for (int h = 0; h < 2; ++h)
#pragma unroll
    for (int j = 0; j < 2; ++j) {
      const int rowS = w * 16 + j * 8 + (lane >> 3);
      const int colE = ((lane & 7) ^ (rowS & 7)) * 8;
      aoff[h][j] = (u32)(m0 + h * 128 + rowS) * (u32)K + (u32)colE;
      boff[h][j] = (u32)(n0 + h * 128 + rowS) * (u32)K + (u32)colE;
    }
  const u32 stW = (u32)w * 1024u;

  const u32 sl0 = (u32)((q ^ (c & 7)) * 8);
  const u32 aR = (u32)(wm * 8192 + c * 64) + sl0;
  const u32 bR = (u32)(16384 + (wn >> 1) * 8192 + (wn & 1) * 4096 + c * 64) + sl0;

  f32x4 acc[8][4];
#pragma unroll
  for (int i2 = 0; i2 < 8; ++i2)
#pragma unroll
    for (int j2 = 0; j2 < 4; ++j2) acc[i2][j2] = (f32x4){0.f, 0.f, 0.f, 0.f};

  const int nt = K >> 6;

#define STG_A(bb, hh, kt)                                                \
  do {                                                                   \
    u16* d_ = &lds[(bb) * 32768u + (hh) * 8192u + stW];                  \
    load_lds16(A + (aoff[hh][0] + (u32)(kt) * 64u), d_);                 \
    load_lds16(A + (aoff[hh][1] + (u32)(kt) * 64u), d_ + 512);           \
  } while (0)
#define STG_B(bb, hh, kt)                                                \
  do {                                                                   \
    u16* d_ = &lds[(bb) * 32768u + 16384u + (hh) * 8192u + stW];         \
    load_lds16(Bt + (boff[hh][0] + (u32)(kt) * 64u), d_);                \
    load_lds16(Bt + (boff[hh][1] + (u32)(kt) * 64u), d_ + 512);          \
  } while (0)
#define RD4(dst, base)                                                   \
  do {                                                                   \
    const u16* p_ = &lds[(base)];                                        \
    dst[0] = *(const bf16x8*)(p_);                                       \
    dst[1] = *(const bf16x8*)(p_ + 1024);                                \
    dst[2] = *(const bf16x8*)(p_ + 2048);                                \
    dst[3] = *(const bf16x8*)(p_ + 3072);                                \
  } while (0)
#define BAR __builtin_amdgcn_s_barrier()
#define LGKM0 asm volatile("s_waitcnt lgkmcnt(0)" ::: "memory")
#define LGKM8 asm volatile("s_waitcnt lgkmcnt(8)" ::: "memory")
#define VM6 asm volatile("s_waitcnt vmcnt(6)" ::: "memory")
#define PRIO1 __builtin_amdgcn_s_setprio(1)
#define PRIO0 __builtin_amdgcn_s_setprio(0)

  STG_B(0, 0, 0);
  STG_B(0, 1, 0);
  STG_A(0, 0, 0);
  STG_A(0, 1, 0);
  STG_B(1, 0, 1);
  STG_B(1, 1, 1);
  STG_A(1, 0, 1);
  VM6;
  BAR;

  bf16x8 Bf0[4], Bf1[4], Af0[4], Af1[4];

  for (int i = 0; i < (nt >> 1); ++i) {
    const int tb = 2 * i + 1;
    int t2 = 2 * i + 2; if (t2 >= nt) t2 -= nt;
    int t3 = 2 * i + 3; if (t3 >= nt) t3 -= nt;

    RD4(Bf0, bR);
    RD4(Bf1, bR ^ 32u);
    RD4(Af0, aR);
    STG_A(1, 1, tb);
    LGKM8;
    BAR; LGKM0;
    PRIO1; mm16<0>(acc, Af0, Bf0); PRIO0;
    BAR;
    RD4(Af1, aR + 4096u);
    STG_B(0, 0, t2);
    BAR; LGKM0;
    PRIO1; mm16<4>(acc, Af1, Bf0); PRIO0;
    BAR;
    RD4(Af0, aR ^ 32u);
    RD4(Af1, (aR + 4096u) ^ 32u);
    STG_B(0, 1, t2);
    BAR; LGKM0;
    PRIO1; mm16<0>(acc, Af0, Bf1); PRIO0;
    BAR;
    STG_A(0, 0, t2);
    VM6;
    BAR;
    PRIO1; mm16<4>(acc, Af1, Bf1); PRIO0;
    BAR;

    RD4(Bf0, 32768u + bR);
    RD4(Bf1, (32768u + bR) ^ 32u);
    RD4(Af0, 32768u + aR);
    STG_A(0, 1, t2);
    LGKM8;
    BAR; LGKM0;
    PRIO1; mm16<0>(acc, Af0, Bf0); PRIO0;
    BAR;
    RD4(Af1, 32768u + aR + 4096u);
    STG_B(1, 0, t3);
    BAR; LGKM0;
    PRIO1; mm16<4>(acc, Af1, Bf0); PRIO0;
    BAR;
    RD4(Af0, (32768u + aR) ^ 32u);
    RD4(Af1, (32768u + aR + 4096u) ^ 32u);
    STG_B(1, 1, t3);
    BAR; LGKM0;
    PRIO1; mm16<0>(acc, Af0, Bf1); PRIO0;
    BAR;
    STG_A(1, 0, t3);
    VM6;
    BAR;
    PRIO1; mm16<4>(acc, Af1, Bf1); PRIO0;
    BAR;
  }

  asm volatile("s_waitcnt vmcnt(0)" ::: "memory");

#undef STG_A
#undef STG_B
#undef RD4
#undef BAR
#undef LGKM0
#undef LGKM8
#undef VM6
#undef PRIO1
#undef PRIO0

  const int rb0 = m0 + wm * 128 + q * 4;
  const int cb0 = n0 + wn * 64 + c;
#pragma unroll
  for (int mf = 0; mf < 8; ++mf)
#pragma unroll
    for (int nf = 0; nf < 4; ++nf) {
      const size_t base = (size_t)(rb0 + mf * 16) * N + (cb0 + nf * 16);
#pragma unroll
      for (int r = 0; r < 4; ++r) {
        if (OUT_BF16)
          ((u16*)Cout)[base + (size_t)r * N] = f2bf(acc[mf][nf][r]);
        else
          ((float*)Cout)[base + (size_t)r * N] = acc[mf][nf][r];
      }
    }
}

// ---------------------------------------------------------------- qkv postprocess
__global__ __launch_bounds__(256) void qkv_post(const u16* __restrict__ raw,
                                                u16* __restrict__ qb,
                                                u16* __restrict__ kb) {
  const int t = threadIdx.x;
  const int c = t & 15, g = t >> 4;
  const u32 u = (u32)blockIdx.x * 16u + (u32)g;   // u < 163840
  const u32 row = u / 40u;
  const int hh = (int)(u - row * 40u);            // 0..39 (q:0-31, k:32-39)
  const int pos = (int)(row & 2047u);
  const int b = (int)(row >> 11);

  const uint4 rv = *(const uint4*)(raw + (size_t)row * 6144 + hh * 128 + c * 8);
  u32 rw[4] = {rv.x, rv.y, rv.z, rv.w};
  float xs[8];
#pragma unroll
  for (int j = 0; j < 4; ++j) {
    xs[2 * j] = bf2f((u16)(rw[j] & 0xffffu));
    xs[2 * j + 1] = bf2f((u16)(rw[j] >> 16));
  }
  float ss = 0.f;
#pragma unroll
  for (int j = 0; j < 8; ++j) ss += xs[j] * xs[j];
#pragma unroll
  for (int off = 8; off >= 1; off >>= 1) ss += __shfl_xor(ss, off);
  const float rn = rsqrtf(ss * (1.0f / 128.0f) + 1e-6f);

  u32 pw[4];
#pragma unroll
  for (int j = 0; j < 4; ++j) pw[j] = __shfl_xor(rw[j], 8);
  float xp[8];
#pragma unroll
  for (int j = 0; j < 4; ++j) {
    xp[2 * j] = bf2f((u16)(pw[j] & 0xffffu));
    xp[2 * j + 1] = bf2f((u16)(pw[j] >> 16));
  }

  const float sgn = (c < 8) ? -1.0f : 1.0f;
  const int dbase = (c & 7) * 8;
  const float fpos = (float)pos;
  const bool isq = (hh < 32);
  const float sc = (isq ? 0.088388347648318447f : 1.0f) * rn;
  float o[8];
#pragma unroll
  for (int j = 0; j < 8; ++j) {
    const float fr = exp2f(-(float)(dbase + j) * 0.20762050593046f);
    float sn, cs;
    sincosf(fpos * fr, &sn, &cs);
    o[j] = (xs[j] * cs + sgn * xp[j] * sn) * sc;
  }

  uint4 ov;
  ov.x = (u32)f2bf(o[0]) | ((u32)f2bf(o[1]) << 16);
  ov.y = (u32)f2bf(o[2]) | ((u32)f2bf(o[3]) << 16);
  ov.z = (u32)f2bf(o[4]) | ((u32)f2bf(o[5]) << 16);
  ov.w = (u32)f2bf(o[6]) | ((u32)f2bf(o[7]) << 16);
  u16* dst = isq ? (qb + ((size_t)((b * 32 + hh) * 2048 + pos)) * 128)
                 : (kb + ((size_t)((b * 8 + (hh - 32)) * 2048 + pos)) * 128);
  *(uint4*)(dst + c * 8) = ov;
}

// ---------------------------------------------------------------- flash attention
// R12 v4: BARRIER-FREE. Each wave independent: 16 queries; K/V fragments
// read directly from global (L2-resident planes). Fragment global slots
// equal what R6's verified LDS swizzle resolved to (layout logic unchanged).
// Wave-private LDS only for the P C->A transpose (same-wave DS ordering).
__global__ __launch_bounds__(256, 4) void attn_fwd(const u16* __restrict__ qb,
                                                   const u16* __restrict__ kb,
                                                   const u16* __restrict__ vtb,
                                                   u16* __restrict__ attn) {
  __shared__ __align__(16) u16 Ps[4][16 * 64];  // wave-private [query][key], swizzled

  const int t = threadIdx.x, lane = t & 63, w = t >> 6;
  const int c = lane & 15, quad = lane >> 4;
  const int q0 = blockIdx.x * 64 + w * 16;      // this wave's query strip
  const int bh = blockIdx.y;
  const int b = bh >> 5, hq = bh & 31;
  const int kvp = b * 8 + (hq >> 2);
  const u16* qp = qb + (size_t)bh * (2048 * 128);
  const u16* kp = kb + (size_t)kvp * (2048 * 128);
  const u16* vp = vtb + (size_t)kvp * (128 * 2048);
  u16* Psw = &Ps[w][0];

  // Q fragments: query = q0 + c; qf[ks]: d = ks*32 + quad*8 .. +7
  bf16x8 qf[4];
  {
    const u16* qrow = qp + (size_t)(q0 + c) * 128 + quad * 8;
#pragma unroll
    for (int ks = 0; ks < 4; ++ks) qf[ks] = *(const bf16x8*)(qrow + ks * 32);
  }

  f32x4 oacc[8];
#pragma unroll
  for (int j = 0; j < 8; ++j)
#pragma unroll
    for (int r = 0; r < 4; ++r) oacc[j][r] = 0.0f;
  float lsum = 0.0f;

  const int iq = q0 + c;

  int t0 = q0 - 1023;
  if (t0 < 0) t0 = 0;
  t0 = (t0 >> 6) << 6;
  const int kvmax = ((q0 + 15) >> 6) << 6;   // last tile containing valid keys

  for (int kv0 = t0; kv0 <= kvmax; kv0 += 64) {
    // ---- S^T = K * Q^T : 64 keys x 16 queries; K frags direct from global
    f32x4 sacc[4];
#pragma unroll
    for (int im = 0; im < 4; ++im)
#pragma unroll
      for (int r = 0; r < 4; ++r) sacc[im][r] = 0.0f;

#pragma unroll
    for (int ks = 0; ks < 4; ++ks) {
#pragma unroll
      for (int im = 0; im < 4; ++im) {
        const bf16x8 af = *(const bf16x8*)(kp + (size_t)(kv0 + im * 16 + c) * 128 +
                                           (ks * 4 + quad) * 8);
        sacc[im] = __builtin_amdgcn_mfma_f32_16x16x32_bf16(af, qf[ks], sacc[im], 0, 0, 0);
      }
    }

    // mask iff tile straddles diagonal (kv0+63 > q0) or window edge
    const bool need_mask = (kv0 + 63 > q0) || (kv0 + 1008 < q0);
#pragma unroll
    for (int im = 0; im < 4; ++im) {
      float pv[4];
#pragma unroll
      for (int r = 0; r < 4; ++r) {
        const float s = sacc[im][r];
        const float u = s * s;
        // 50*tanh(s/50) = s*(1 - u/7500 + 2u^2/9.375e7), |s|<=11.4
        const float cap = s * (1.0f + u * (-1.3333333e-4f + u * 2.1333333e-8f));
        pv[r] = __expf(cap);
      }
      if (need_mask) {
        const int j_base = kv0 + im * 16 + quad * 4;
#pragma unroll
        for (int r = 0; r < 4; ++r) {
          const int j_glob = j_base + r;
          if (!((j_glob <= iq) && (iq - j_glob < 1024))) pv[r] = 0.0f;
        }
      }
      lsum += (pv[0] + pv[1]) + (pv[2] + pv[3]);
      // keys im*16+quad*4+{0..3} of query c -> chunk im*2+(quad>>1), half quad&1,
      // stored at phys chunk ^(c&7)  (wave-private; no barrier needed)
      uint2 pk;
      pk.x = pack_trunc(pv[0], pv[1]);
      pk.y = pack_trunc(pv[2], pv[3]);
      *(uint2*)&Psw[c * 64 + ((im * 2 + (quad >> 1)) ^ (c & 7)) * 8 + (quad & 1) * 4] = pk;
    }

    // ---- PV: A = P (wave-private LDS), B = V^T frags direct from global
#pragma unroll
    for (int ks = 0; ks < 2; ++ks) {
      const bf16x8 pf = *(const bf16x8*)&Psw[c * 64 + ((ks * 4 + quad) ^ (c & 7)) * 8];
#pragma unroll
      for (int jn = 0; jn < 8; ++jn) {
        const bf16x8 vf = *(const bf16x8*)(vp + (size_t)(jn * 16 + c) * 2048 + kv0 +
                                           (ks * 4 + quad) * 8);
        oacc[jn] = __builtin_amdgcn_mfma_f32_16x16x32_bf16(pf, vf, oacc[jn], 0, 0, 0);
      }
    }
  }

  // ---- normalize + store (cross-quad shuffle reduce; wave-internal)
  float lt = lsum;
  lt += __shfl_xor(lt, 16);
  lt += __shfl_xor(lt, 32);
  float rl[4];
#pragma unroll
  for (int r = 0; r < 4; ++r)
    rl[r] = __builtin_amdgcn_rcpf(__shfl(lt, quad * 4 + r));

  const size_t obase = ((size_t)(b * 2048 + q0)) * 4096 + hq * 128;
#pragma unroll
  for (int jn = 0; jn < 8; ++jn) {
#pragma unroll
    for (int r = 0; r < 4; ++r) {
      const int q_in = quad * 4 + r;
      attn[obase + (size_t)q_in * 4096 + jn * 16 + c] = f2bf(oacc[jn][r] * rl[r]);
    }
  }
}

// ---------------------------------------------------------------- launch
extern "C" void kernel_launch(void* const* d_in, const int* in_sizes, int n_in,
                              void* d_out, int out_size, void* d_ws, size_t ws_size,
                              hipStream_t stream) {
  (void)in_sizes; (void)n_in; (void)out_size; (void)ws_size;
  const float* x  = (const float*)d_in[0];
  const float* Wq = (const float*)d_in[1];
  const float* Wk = (const float*)d_in[2];
  const float* Wv = (const float*)d_in[3];
  const float* Wo = (const float*)d_in[4];
  float* out = (float*)d_out;
  char* ws = (char*)d_ws;

  u16* xb    = (u16*)(ws + 0);
  u16* vtb   = (u16*)(ws + 0);
  u16* WqkvT = (u16*)(ws + 33554432ULL);
  u16* qb    = (u16*)(ws + 33554432ULL);
  u16* kb    = (u16*)(ws + 67108864ULL);
  u16* WoT   = (u16*)(ws + 83886080ULL);
  u16* qkvr  = (u16*)(ws + 117440512ULL);
  u16* attnb = (u16*)(ws + 117440512ULL);

  cast_f32_bf16<<<8192, 256, 0, stream>>>(x, xb);
  transpose_cast_f32_bf16<<<dim3(128, 128), 256, 0, stream>>>(Wq, WqkvT, 4096, 4096);
  transpose_cast_f32_bf16<<<dim3(32, 128), 256, 0, stream>>>(Wk, WqkvT + (size_t)4096 * 4096, 4096, 1024);
  transpose_cast_f32_bf16<<<dim3(32, 128), 256, 0, stream>>>(Wv, WqkvT + (size_t)5120 * 4096, 4096, 1024);
  transpose_cast_f32_bf16<<<dim3(128, 128), 256, 0, stream>>>(Wo, WoT, 4096, 4096);

  // QKV: M=4096, N=6144, K=4096 -> 16x24 = 384 tiles (384 % 8 == 0)
  gemm256<1><<<dim3(384), 512, 0, stream>>>(xb, WqkvT, (void*)qkvr, 6144, 4096, 24);
  qkv_post<<<10240, 256, 0, stream>>>(qkvr, qb, kb);
  transpose_v<<<dim3(64, 4, 16), 256, 0, stream>>>(qkvr, vtb);
  attn_fwd<<<dim3(32, 64), 256, 0, stream>>>(qb, kb, vtb, attnb);
  // Out: M=4096, N=4096, K=4096 -> 16x16 = 256 tiles (1.0 rounds)
  gemm256<0><<<dim3(256), 512, 0, stream>>>(attnb, WoT, (void*)out, 4096, 4096, 16);
}